// Round 6
// baseline (1167.403 us; speedup 1.0000x reference)
//
#include <hip/hip_runtime.h>
#include <hip/hip_bf16.h>

// N=100000, E=1600000. N % 16 == 0 -> grids divide exactly.
// Gather tables bf16. agg1 uses packed gathers (4 edges per VMEM instr).
// Encoder uses LDS-staged K/V (float4) instead of shuffles.

#define NEG_SLOPE 0.2f

// ---------------------------------------------------------------------------
// Fused front kernel: blocks [0,EB) encoder, [EB,EB+CB) count, rest xw1.
// ---------------------------------------------------------------------------
__global__ void __launch_bounds__(256) front_kernel(
    // encoder args
    const float* __restrict__ Xf,
    const float* __restrict__ Wq, const float* __restrict__ bq,
    const float* __restrict__ Wk, const float* __restrict__ bk,
    const float* __restrict__ Wv, const float* __restrict__ bv,
    const float* __restrict__ g0, const float* __restrict__ be0,
    const float* __restrict__ Wf1, const float* __restrict__ bf1,
    const float* __restrict__ Wf2, const float* __restrict__ bf2,
    const float* __restrict__ g1, const float* __restrict__ be1,
    const float* __restrict__ Wrep, const float* __restrict__ brep,
    float* __restrict__ xt,
    // count args
    const int* __restrict__ src, const int* __restrict__ dst,
    int* __restrict__ deg, int e,
    // xw1 args
    const float* __restrict__ x, const float* __restrict__ W1,
    const float* __restrict__ att1,
    __hip_bfloat16* __restrict__ xwb,
    float* __restrict__ ai, float* __restrict__ aj,
    int n, int EB, int CB)
{
    __shared__ float smem[4352];
    int t = threadIdx.x;
    int bid = blockIdx.x;

    if (bid < EB) {
        // ----------------- encoder: 8 nodes per block -----------------
        float* sh = smem;
        size_t base = (size_t)bid * 2560;
#pragma unroll
        for (int i = 0; i < 10; ++i) sh[i * 256 + t] = Xf[base + i * 256 + t];
        __syncthreads();

        int sub = t >> 5;
        int s   = t & 31;
        int v   = bid * 8 + sub;

        float xv[10];
#pragma unroll
        for (int i = 0; i < 10; ++i) xv[i] = sh[sub * 320 + s * 10 + i];
        __syncthreads();   // Xf fully consumed; slab will be reused for K/V

        float q[6], k[6], w[6];
#pragma unroll
        for (int j = 0; j < 6; ++j) { q[j] = bq[j]; k[j] = bk[j]; w[j] = bv[j]; }
#pragma unroll
        for (int i = 0; i < 10; ++i) {
#pragma unroll
            for (int j = 0; j < 6; ++j) {
                q[j] += xv[i] * Wq[i * 6 + j];
                k[j] += xv[i] * Wk[i * 6 + j];
                w[j] += xv[i] * Wv[i * 6 + j];
            }
        }

        // K/V slab per node: [2 heads][32 tokens][8 floats] = 512 floats.
        // Written and read by the same wave only -> no block barrier needed.
        int kvb = sub * 512 + s * 8;
        *(float4*)&sh[kvb      ] = make_float4(k[0], k[1], k[2], 0.f);
        *(float4*)&sh[kvb +   4] = make_float4(w[0], w[1], w[2], 0.f);
        *(float4*)&sh[kvb + 256] = make_float4(k[3], k[4], k[5], 0.f);
        *(float4*)&sh[kvb + 260] = make_float4(w[3], w[4], w[5], 0.f);
        __builtin_amdgcn_wave_barrier();

        // logits |.| << 1 -> no max subtraction needed
        const float scale = 0.40824829046386301637f;  // 1/sqrt(6)
        float O[6];
#pragma unroll
        for (int hh = 0; hh < 2; ++hh) {
            const float q0 = q[hh * 3 + 0] * scale;
            const float q1 = q[hh * 3 + 1] * scale;
            const float q2 = q[hh * 3 + 2] * scale;
            int kb = sub * 512 + hh * 256;
            float dA = 0.f, dB = 0.f;
            float aA0 = 0.f, aA1 = 0.f, aA2 = 0.f;
            float aB0 = 0.f, aB1 = 0.f, aB2 = 0.f;
#pragma unroll
            for (int t2 = 0; t2 < 32; t2 += 2) {
                float4 kk0 = *(const float4*)&sh[kb + t2 * 8];
                float4 vv0 = *(const float4*)&sh[kb + t2 * 8 + 4];
                float4 kk1 = *(const float4*)&sh[kb + t2 * 8 + 8];
                float4 vv1 = *(const float4*)&sh[kb + t2 * 8 + 12];
                float p0 = __expf(q0 * kk0.x + q1 * kk0.y + q2 * kk0.z);
                float p1 = __expf(q0 * kk1.x + q1 * kk1.y + q2 * kk1.z);
                dA += p0; aA0 += p0 * vv0.x; aA1 += p0 * vv0.y; aA2 += p0 * vv0.z;
                dB += p1; aB0 += p1 * vv1.x; aB1 += p1 * vv1.y; aB2 += p1 * vv1.z;
            }
            float inv = 1.f / (dA + dB);
            O[hh * 3 + 0] = q[hh * 3 + 0] + (aA0 + aB0) * inv;
            O[hh * 3 + 1] = q[hh * 3 + 1] + (aA1 + aB1) * inv;
            O[hh * 3 + 2] = q[hh * 3 + 2] + (aA2 + aB2) * inv;
        }

        {
            float mean = (O[0] + O[1] + O[2] + O[3] + O[4] + O[5]) * (1.f / 6.f);
            float var = 0.f;
#pragma unroll
            for (int j = 0; j < 6; ++j) { float d = O[j] - mean; var += d * d; }
            var *= (1.f / 6.f);
            float r = 1.f / sqrtf(var + 1e-5f);
#pragma unroll
            for (int j = 0; j < 6; ++j) O[j] = (O[j] - mean) * r * g0[j] + be0[j];
        }

        float f[6];
        {
            float hbuf[24];
#pragma unroll
            for (int r = 0; r < 24; ++r) {
                float tt = bf1[r];
#pragma unroll
                for (int j = 0; j < 6; ++j) tt += O[j] * Wf1[j * 24 + r];
                hbuf[r] = fmaxf(tt, 0.f);
            }
#pragma unroll
            for (int j = 0; j < 6; ++j) {
                float tt = bf2[j];
#pragma unroll
                for (int r = 0; r < 24; ++r) tt += hbuf[r] * Wf2[r * 6 + j];
                f[j] = O[j] + tt;
            }
        }
        {
            float mean = (f[0] + f[1] + f[2] + f[3] + f[4] + f[5]) * (1.f / 6.f);
            float var = 0.f;
#pragma unroll
            for (int j = 0; j < 6; ++j) { float d = f[j] - mean; var += d * d; }
            var *= (1.f / 6.f);
            float r = 1.f / sqrtf(var + 1e-5f);
#pragma unroll
            for (int j = 0; j < 6; ++j) f[j] = (f[j] - mean) * r * g1[j] + be1[j];
        }

        float wr = Wrep[s];
#pragma unroll
        for (int j = 0; j < 6; ++j) {
            float val = f[j] * wr;
#pragma unroll
            for (int off = 16; off >= 1; off >>= 1) val += __shfl_xor(val, off, 32);
            f[j] = val;
        }
        if (s == 0) {
            float br = brep[0];
#pragma unroll
            for (int j = 0; j < 6; ++j) xt[(size_t)v * 6 + j] = f[j] + br;
        }
    } else if (bid < EB + CB) {
        // ----------------- count: degree histogram -----------------
        int i = (bid - EB) * 256 + t;
        if (i < e) {
            int ss = src[i], dd = dst[i];
            if (ss != dd) atomicAdd(&deg[dd], 1);
        }
    } else {
        // ----------------- xw1: 16 nodes per block -----------------
        float* shW = smem;                         // 4096 floats
        float* shX = smem + 4096;                  // 256 floats
        int xb = bid - EB - CB;
        int wv = t >> 6, l = t & 63;
#pragma unroll
        for (int i = 0; i < 16; ++i) shW[i * 256 + t] = W1[i * 256 + t];
        int h = l >> 3, c = l & 7;
        float a_i = att1[h * 16 + c];
        float a_j = att1[h * 16 + 8 + c];
        __syncthreads();

#pragma unroll
        for (int it = 0; it < 4; ++it) {
            int v = xb * 16 + it * 4 + wv;
            shX[wv * 64 + l] = x[(size_t)v * 64 + l];
            __builtin_amdgcn_wave_barrier();
            float acc = 0.f;
#pragma unroll
            for (int k4 = 0; k4 < 16; ++k4) {
                float4 xb4 = *(const float4*)&shX[wv * 64 + k4 * 4];
                acc += xb4.x * shW[(k4 * 4 + 0) * 64 + l];
                acc += xb4.y * shW[(k4 * 4 + 1) * 64 + l];
                acc += xb4.z * shW[(k4 * 4 + 2) * 64 + l];
                acc += xb4.w * shW[(k4 * 4 + 3) * 64 + l];
            }
            xwb[(size_t)v * 64 + l] = __float2bfloat16(acc);

            float pi = acc * a_i;
            float pj = acc * a_j;
#pragma unroll
            for (int off = 1; off < 8; off <<= 1) {
                pi += __shfl_xor(pi, off, 64);
                pj += __shfl_xor(pj, off, 64);
            }
            if (c == 0) {
                ai[(size_t)v * 8 + h] = pi;
                aj[(size_t)v * 8 + h] = pj;
            }
            __builtin_amdgcn_wave_barrier();
        }
    }
}

// ---------------------------------------------------------------------------
// scan: exclusive prefix over degrees (single block, 1024 threads)
// ---------------------------------------------------------------------------
__global__ void __launch_bounds__(1024) scan_kernel(
    const int* __restrict__ deg, int* __restrict__ offsets, int n)
{
    __shared__ int sums[1024];
    int t = threadIdx.x;
    int ch = (n + 1023) >> 10;
    int start = t * ch;
    int end = min(start + ch, n);
    int local = 0;
    for (int i = start; i < end; ++i) local += deg[i];
    sums[t] = local;
    __syncthreads();
    for (int off = 1; off < 1024; off <<= 1) {
        int val = (t >= off) ? sums[t - off] : 0;
        __syncthreads();
        sums[t] += val;
        __syncthreads();
    }
    int run = sums[t] - local;  // exclusive prefix
    for (int i = start; i < end; ++i) { offsets[i] = run; run += deg[i]; }
}

__global__ void scatter_kernel(const int* __restrict__ src, const int* __restrict__ dst,
                               const int* __restrict__ offsets, int* __restrict__ cursor,
                               int* __restrict__ elist, int e)
{
    int i = blockIdx.x * blockDim.x + threadIdx.x;
    if (i < e) {
        int s = src[i], d = dst[i];
        if (s != d) {
            int pos = offsets[d] + atomicAdd(&cursor[d], 1);
            elist[pos] = s;
        }
    }
}

// ---------------------------------------------------------------------------
// Fused GAT-1 aggregation (packed gathers) + ELU + xw2 + layer-2 dots.
// 16 nodes per block (4 per wave, sequential) -> W2 staging amortized 4x.
// Lane l = (edge-slot e=l>>4, feature-quad q=l&15) during gather.
// ---------------------------------------------------------------------------
__global__ void __launch_bounds__(256) agg1_fused_kernel(
    const __hip_bfloat16* __restrict__ xwb, const float* __restrict__ ai1,
    const float* __restrict__ aj1, const float* __restrict__ b1,
    const float* __restrict__ xt, const float* __restrict__ W2,
    const float* __restrict__ att2,
    const int* __restrict__ offs, const int* __restrict__ deg,
    const int* __restrict__ elist,
    __hip_bfloat16* __restrict__ xw2b,
    float* __restrict__ ai2, float* __restrict__ aj2,
    int n)
{
    __shared__ float shW2[5600];
    __shared__ float shH[4][72];    // 64 h1 + 6 xt, per wave
    __shared__ float shR[4][80];    // xw2 row, per wave
    __shared__ float shAcc[4][64];  // packed->linear realign, per wave
    __shared__ float shDen[4][8];
    int t = threadIdx.x, wv = t >> 6, l = t & 63;
    for (int i = t; i < 5600; i += 256) shW2[i] = W2[i];
    __syncthreads();

    // packed-layout identities (loop-invariant)
    int eg = l >> 4;        // edge slot 0..3
    int q  = l & 15;        // feature quad (features 4q..4q+3)
    int hq = q >> 1;        // head of this quad (C1=8 -> quad-pure)
    int h  = l >> 3;
    float b1l = b1[l];

#pragma unroll
    for (int it = 0; it < 4; ++it) {
        int v = blockIdx.x * 16 + it * 4 + wv;

        float ai_hq = ai1[(size_t)v * 8 + hq];
        float acc4[4] = {0.f, 0.f, 0.f, 0.f};
        float den = 0.f;

        int off = offs[v], dg = deg[v];
        for (int j = 0; j < dg; j += 16) {
            int idxv = 0;
            if (l < 16 && j + l < dg) idxv = elist[off + j + l];
#pragma unroll
            for (int g = 0; g < 4; ++g) {
                int s = __shfl(idxv, g * 4 + eg, 64);
                bool valid = (j + g * 4 + eg) < dg;
                float ajv = aj1[(size_t)s * 8 + hq];
                unsigned long long y8 =
                    *(const unsigned long long*)(xwb + (size_t)s * 64 + q * 4);
                float aa = ai_hq + ajv;
                aa = aa >= 0.f ? aa : NEG_SLOPE * aa;
                float w = valid ? __expf(aa) : 0.f;
                float y0 = __uint_as_float((unsigned)(y8 & 0xffffull) << 16);
                float y1 = __uint_as_float((unsigned)((y8 >> 16) & 0xffffull) << 16);
                float y2 = __uint_as_float((unsigned)((y8 >> 32) & 0xffffull) << 16);
                float y3 = __uint_as_float((unsigned)(y8 >> 48) << 16);
                acc4[0] += w * y0;
                acc4[1] += w * y1;
                acc4[2] += w * y2;
                acc4[3] += w * y3;
                den += w;
            }
        }

        // reduce over the 4 edge-groups (lanes l, l^16, l^32, l^48)
#pragma unroll
        for (int kk = 0; kk < 4; ++kk) {
            acc4[kk] += __shfl_xor(acc4[kk], 16, 64);
            acc4[kk] += __shfl_xor(acc4[kk], 32, 64);
        }
        den += __shfl_xor(den, 16, 64);
        den += __shfl_xor(den, 32, 64);

        // realign to feature-per-lane via per-wave LDS slab
        if (l < 16) {
#pragma unroll
            for (int kk = 0; kk < 4; ++kk) shAcc[wv][q * 4 + kk] = acc4[kk];
            if ((q & 1) == 0) shDen[wv][hq] = den;
        }
        __builtin_amdgcn_wave_barrier();

        float acc = shAcc[wv][l];
        float dn  = shDen[wv][h];

        // self loop (linear layout)
        float aiv = ai1[(size_t)v * 8 + h];
        float a = aiv + aj1[(size_t)v * 8 + h];
        a = a >= 0.f ? a : NEG_SLOPE * a;
        float ea = __expf(a);
        acc += ea * __bfloat162float(xwb[(size_t)v * 64 + l]);
        dn  += ea;

        float o = acc / dn + b1l;
        o = o > 0.f ? o : expm1f(o);   // elu -> h1[v][l], stays on chip

        shH[wv][l] = o;
        if (l < 6) shH[wv][64 + l] = xt[(size_t)v * 6 + l];
        __builtin_amdgcn_wave_barrier();

        // xw2 row = concat(h1, xt) @ W2 ; lane l -> cols l and (l<16) 64+l
        float a0 = 0.f, a1 = 0.f;
#pragma unroll
        for (int kk = 0; kk < 70; ++kk) {
            float f = shH[wv][kk];
            a0 += f * shW2[kk * 80 + l];
            if (l < 16) a1 += f * shW2[kk * 80 + 64 + l];
        }
        xw2b[(size_t)v * 80 + l] = __float2bfloat16(a0);
        shR[wv][l] = a0;
        if (l < 16) {
            xw2b[(size_t)v * 80 + 64 + l] = __float2bfloat16(a1);
            shR[wv][64 + l] = a1;
        }
        __builtin_amdgcn_wave_barrier();

        if (l < 16) {
            int hh = l >> 1, wj = l & 1;
            float sdot = 0.f;
#pragma unroll
            for (int cc = 0; cc < 10; ++cc)
                sdot += shR[wv][hh * 10 + cc] * att2[hh * 20 + wj * 10 + cc];
            if (wj == 0) ai2[(size_t)v * 8 + hh] = sdot;
            else         aj2[(size_t)v * 8 + hh] = sdot;
        }
        __builtin_amdgcn_wave_barrier();
    }
}

// ---------------------------------------------------------------------------
// GAT layer 2 aggregation (bf16 table) + head-mean + b2 + log_softmax.
// 4 nodes per wave (sequential), grid n/16.
// ---------------------------------------------------------------------------
__global__ void __launch_bounds__(256) agg2_kernel(
    const __hip_bfloat16* __restrict__ xw2b, const float* __restrict__ ai,
    const float* __restrict__ aj, const float* __restrict__ b2,
    const int* __restrict__ offs, const int* __restrict__ deg,
    const int* __restrict__ elist, float* __restrict__ out, int n)
{
    __shared__ float buf[4][80];
    __shared__ float buf2[4][10];
    int tid = threadIdx.x;
    int wv  = tid >> 6;
    int l   = tid & 63;

    int h0  = l / 10;
    int s1  = l + 64;
    int h1i = s1 / 10;
    float b2l = (l < 10) ? b2[l] : 0.f;

#pragma unroll
    for (int it = 0; it < 4; ++it) {
        int v = blockIdx.x * 16 + it * 4 + wv;

        float ai0  = ai[(size_t)v * 8 + h0];
        float aj0  = aj[(size_t)v * 8 + h0];
        float ai1v = (l < 16) ? ai[(size_t)v * 8 + h1i] : 0.f;
        float aj1v = (l < 16) ? aj[(size_t)v * 8 + h1i] : 0.f;
        float x0 = __bfloat162float(xw2b[(size_t)v * 80 + l]);
        float x1 = (l < 16) ? __bfloat162float(xw2b[(size_t)v * 80 + s1]) : 0.f;

        float t0 = ai0 + aj0;   t0 = t0 >= 0.f ? t0 : NEG_SLOPE * t0;
        float t1 = ai1v + aj1v; t1 = t1 >= 0.f ? t1 : NEG_SLOPE * t1;
        float e0 = __expf(t0), e1 = __expf(t1);
        float acc0 = e0 * x0, den0 = e0;
        float acc1 = e1 * x1, den1 = e1;

        int off = offs[v], dg = deg[v];
        for (int j = 0; j < dg; j += 8) {
            int idxv = 0;
            if (l < 8 && j + l < dg) idxv = elist[off + j + l];
            float p[8], y[8], qq[8], z[8];
#pragma unroll
            for (int b = 0; b < 8; ++b) {
                int s = __shfl(idxv, b, 64);
                p[b] = aj[(size_t)s * 8 + h0];
                y[b] = __bfloat162float(xw2b[(size_t)s * 80 + l]);
                qq[b] = (l < 16) ? aj[(size_t)s * 8 + h1i] : 0.f;
                z[b] = (l < 16) ? __bfloat162float(xw2b[(size_t)s * 80 + s1]) : 0.f;
            }
#pragma unroll
            for (int b = 0; b < 8; ++b) {
                if (j + b < dg) {                 // scalar condition
                    float u = ai0 + p[b]; u = u >= 0.f ? u : NEG_SLOPE * u;
                    float w = __expf(u);
                    acc0 += w * y[b];
                    den0 += w;
                    float r = ai1v + qq[b]; r = r >= 0.f ? r : NEG_SLOPE * r;
                    float g = __expf(r);
                    acc1 += g * z[b];
                    den1 += g;
                }
            }
        }
        buf[wv][l] = acc0 / den0;
        if (l < 16) buf[wv][64 + l] = acc1 / den1;
        __builtin_amdgcn_wave_barrier();
        if (l < 10) {
            float mval = 0.f;
#pragma unroll
            for (int hh = 0; hh < 8; ++hh) mval += buf[wv][hh * 10 + l];
            buf2[wv][l] = mval * 0.125f + b2l;
        }
        __builtin_amdgcn_wave_barrier();
        if (l < 10) {
            float mx = -1e30f;
#pragma unroll
            for (int cc = 0; cc < 10; ++cc) mx = fmaxf(mx, buf2[wv][cc]);
            float se = 0.f;
#pragma unroll
            for (int cc = 0; cc < 10; ++cc) se += __expf(buf2[wv][cc] - mx);
            out[(size_t)v * 10 + l] = buf2[wv][l] - mx - __logf(se);
        }
        __builtin_amdgcn_wave_barrier();
    }
}

// ---------------------------------------------------------------------------
extern "C" void kernel_launch(void* const* d_in, const int* in_sizes, int n_in,
                              void* d_out, int out_size, void* d_ws, size_t ws_size,
                              hipStream_t stream)
{
    const float* x    = (const float*)d_in[0];
    const int*   ei   = (const int*)  d_in[1];
    const float* ef   = (const float*)d_in[2];
    const float* W1   = (const float*)d_in[3];
    const float* att1 = (const float*)d_in[4];
    const float* b1   = (const float*)d_in[5];
    const float* W2   = (const float*)d_in[6];
    const float* att2 = (const float*)d_in[7];
    const float* b2   = (const float*)d_in[8];
    const float* Wq   = (const float*)d_in[9];
    const float* bq   = (const float*)d_in[10];
    const float* Wk   = (const float*)d_in[11];
    const float* bk   = (const float*)d_in[12];
    const float* Wv   = (const float*)d_in[13];
    const float* bv   = (const float*)d_in[14];
    const float* g0   = (const float*)d_in[15];
    const float* be0  = (const float*)d_in[16];
    const float* Wf1  = (const float*)d_in[17];
    const float* bf1  = (const float*)d_in[18];
    const float* Wf2  = (const float*)d_in[19];
    const float* bf2  = (const float*)d_in[20];
    const float* g1   = (const float*)d_in[21];
    const float* be1  = (const float*)d_in[22];
    const float* Wrep = (const float*)d_in[23];
    const float* brep = (const float*)d_in[24];

    const int n = in_sizes[0] / 64;   // 100000
    const int e = in_sizes[1] / 2;    // 1600000
    const int* src = ei;
    const int* dst = ei + e;

    char* ws = (char*)d_ws;
    size_t o = 0;
    auto alloc = [&](size_t bytes) -> void* {
        void* p = ws + o;
        o += (bytes + 255) & ~(size_t)255;
        return p;
    };
    __hip_bfloat16* xw1b = (__hip_bfloat16*)alloc((size_t)n * 64 * 2);
    __hip_bfloat16* xw2b = (__hip_bfloat16*)alloc((size_t)n * 80 * 2);
    float* ai1   = (float*)alloc((size_t)n * 8 * 4);
    float* aj1   = (float*)alloc((size_t)n * 8 * 4);
    float* ai2   = (float*)alloc((size_t)n * 8 * 4);
    float* aj2   = (float*)alloc((size_t)n * 8 * 4);
    float* xt    = (float*)alloc((size_t)n * 6 * 4);
    int*   deg   = (int*)  alloc((size_t)n * 4);
    int*   offs  = (int*)  alloc((size_t)n * 4);
    int*   cur   = (int*)  alloc((size_t)n * 4);
    int*   elist = (int*)  alloc((size_t)e * 4);
    (void)ws_size; (void)n_in; (void)out_size;

    hipMemsetAsync(deg, 0, (size_t)n * 4, stream);
    hipMemsetAsync(cur, 0, (size_t)n * 4, stream);

    const int EB = n / 8;                // 12500 encoder blocks
    const int CB = (e + 255) / 256;      // 6250 count blocks
    const int XB = n / 16;               // 6250 xw1 blocks
    front_kernel<<<EB + CB + XB, 256, 0, stream>>>(
        ef, Wq, bq, Wk, bk, Wv, bv, g0, be0, Wf1, bf1, Wf2, bf2, g1, be1,
        Wrep, brep, xt,
        src, dst, deg, e,
        x, W1, att1, xw1b, ai1, aj1,
        n, EB, CB);
    scan_kernel<<<1, 1024, 0, stream>>>(deg, offs, n);
    scatter_kernel<<<(e + 255) / 256, 256, 0, stream>>>(src, dst, offs, cur, elist, e);
    agg1_fused_kernel<<<n / 16, 256, 0, stream>>>(xw1b, ai1, aj1, b1, xt, W2, att2,
                                                  offs, deg, elist, xw2b, ai2, aj2, n);
    agg2_kernel<<<n / 16, 256, 0, stream>>>(xw2b, ai2, aj2, b2, offs, deg, elist,
                                            (float*)d_out, n);
}

// Round 7
// 1050.022 us; speedup vs baseline: 1.1118x; 1.1118x over previous
//
#include <hip/hip_runtime.h>
#include <hip/hip_bf16.h>

// N=100000, E=1600000. Grids divide exactly -> no guards.
// Gather kernels are line-request bound: minimize cache lines touched per edge.
// agg1: 1 line/edge (aj recomputed from the gathered row via shfl reduce).
// agg2: 2 lines/edge (one packed 256B-aligned row: 80 xw2 + 8 aj2, bf16).

#define NEG_SLOPE 0.2f

__device__ __forceinline__ float bf_lo(unsigned u) { return __uint_as_float(u << 16); }
__device__ __forceinline__ float bf_hi(unsigned u) { return __uint_as_float(u & 0xffff0000u); }

// ---------------------------------------------------------------------------
// Fused front kernel: blocks [0,EB) encoder, [EB,EB+CB) count, rest xw1.
// ---------------------------------------------------------------------------
__global__ void __launch_bounds__(256) front_kernel(
    // encoder args
    const float* __restrict__ Xf,
    const float* __restrict__ Wq, const float* __restrict__ bq,
    const float* __restrict__ Wk, const float* __restrict__ bk,
    const float* __restrict__ Wv, const float* __restrict__ bv,
    const float* __restrict__ g0, const float* __restrict__ be0,
    const float* __restrict__ Wf1, const float* __restrict__ bf1,
    const float* __restrict__ Wf2, const float* __restrict__ bf2,
    const float* __restrict__ g1, const float* __restrict__ be1,
    const float* __restrict__ Wrep, const float* __restrict__ brep,
    float* __restrict__ xt,
    // count args
    const int* __restrict__ src, const int* __restrict__ dst,
    int* __restrict__ deg, int e,
    // xw1 args
    const float* __restrict__ x, const float* __restrict__ W1,
    const float* __restrict__ att1,
    __hip_bfloat16* __restrict__ xwb,
    float* __restrict__ ai,
    int n, int EB, int CB)
{
    __shared__ float smem[4352];
    int t = threadIdx.x;
    int bid = blockIdx.x;

    if (bid < EB) {
        // ----------------- encoder: 8 nodes per block -----------------
        float* sh = smem;
        size_t base = (size_t)bid * 2560;
#pragma unroll
        for (int i = 0; i < 10; ++i) sh[i * 256 + t] = Xf[base + i * 256 + t];
        __syncthreads();

        int sub = t >> 5;
        int s   = t & 31;
        int v   = bid * 8 + sub;

        float xv[10];
#pragma unroll
        for (int i = 0; i < 10; ++i) xv[i] = sh[sub * 320 + s * 10 + i];
        __syncthreads();   // Xf consumed; slab reused for K/V

        float q[6], k[6], w[6];
#pragma unroll
        for (int j = 0; j < 6; ++j) { q[j] = bq[j]; k[j] = bk[j]; w[j] = bv[j]; }
#pragma unroll
        for (int i = 0; i < 10; ++i) {
#pragma unroll
            for (int j = 0; j < 6; ++j) {
                q[j] += xv[i] * Wq[i * 6 + j];
                k[j] += xv[i] * Wk[i * 6 + j];
                w[j] += xv[i] * Wv[i * 6 + j];
            }
        }

        // K/V slab: per node [2 heads][32 tokens][8 floats]; same-wave only.
        int kvb = sub * 512 + s * 8;
        *(float4*)&sh[kvb      ] = make_float4(k[0], k[1], k[2], 0.f);
        *(float4*)&sh[kvb +   4] = make_float4(w[0], w[1], w[2], 0.f);
        *(float4*)&sh[kvb + 256] = make_float4(k[3], k[4], k[5], 0.f);
        *(float4*)&sh[kvb + 260] = make_float4(w[3], w[4], w[5], 0.f);
        __builtin_amdgcn_wave_barrier();

        const float scale = 0.40824829046386301637f;  // 1/sqrt(6)
        float O[6];
#pragma unroll
        for (int hh = 0; hh < 2; ++hh) {
            const float q0 = q[hh * 3 + 0] * scale;
            const float q1 = q[hh * 3 + 1] * scale;
            const float q2 = q[hh * 3 + 2] * scale;
            int kb = sub * 512 + hh * 256;
            float dA = 0.f, dB = 0.f;
            float aA0 = 0.f, aA1 = 0.f, aA2 = 0.f;
            float aB0 = 0.f, aB1 = 0.f, aB2 = 0.f;
#pragma unroll
            for (int t2 = 0; t2 < 32; t2 += 2) {
                float4 kk0 = *(const float4*)&sh[kb + t2 * 8];
                float4 vv0 = *(const float4*)&sh[kb + t2 * 8 + 4];
                float4 kk1 = *(const float4*)&sh[kb + t2 * 8 + 8];
                float4 vv1 = *(const float4*)&sh[kb + t2 * 8 + 12];
                float p0 = __expf(q0 * kk0.x + q1 * kk0.y + q2 * kk0.z);
                float p1 = __expf(q0 * kk1.x + q1 * kk1.y + q2 * kk1.z);
                dA += p0; aA0 += p0 * vv0.x; aA1 += p0 * vv0.y; aA2 += p0 * vv0.z;
                dB += p1; aB0 += p1 * vv1.x; aB1 += p1 * vv1.y; aB2 += p1 * vv1.z;
            }
            float inv = 1.f / (dA + dB);
            O[hh * 3 + 0] = q[hh * 3 + 0] + (aA0 + aB0) * inv;
            O[hh * 3 + 1] = q[hh * 3 + 1] + (aA1 + aB1) * inv;
            O[hh * 3 + 2] = q[hh * 3 + 2] + (aA2 + aB2) * inv;
        }

        {
            float mean = (O[0] + O[1] + O[2] + O[3] + O[4] + O[5]) * (1.f / 6.f);
            float var = 0.f;
#pragma unroll
            for (int j = 0; j < 6; ++j) { float d = O[j] - mean; var += d * d; }
            var *= (1.f / 6.f);
            float r = 1.f / sqrtf(var + 1e-5f);
#pragma unroll
            for (int j = 0; j < 6; ++j) O[j] = (O[j] - mean) * r * g0[j] + be0[j];
        }

        float f[6];
        {
            float hbuf[24];
#pragma unroll
            for (int r = 0; r < 24; ++r) {
                float tt = bf1[r];
#pragma unroll
                for (int j = 0; j < 6; ++j) tt += O[j] * Wf1[j * 24 + r];
                hbuf[r] = fmaxf(tt, 0.f);
            }
#pragma unroll
            for (int j = 0; j < 6; ++j) {
                float tt = bf2[j];
#pragma unroll
                for (int r = 0; r < 24; ++r) tt += hbuf[r] * Wf2[r * 6 + j];
                f[j] = O[j] + tt;
            }
        }
        {
            float mean = (f[0] + f[1] + f[2] + f[3] + f[4] + f[5]) * (1.f / 6.f);
            float var = 0.f;
#pragma unroll
            for (int j = 0; j < 6; ++j) { float d = f[j] - mean; var += d * d; }
            var *= (1.f / 6.f);
            float r = 1.f / sqrtf(var + 1e-5f);
#pragma unroll
            for (int j = 0; j < 6; ++j) f[j] = (f[j] - mean) * r * g1[j] + be1[j];
        }

        float wr = Wrep[s];
#pragma unroll
        for (int j = 0; j < 6; ++j) {
            float val = f[j] * wr;
#pragma unroll
            for (int off = 16; off >= 1; off >>= 1) val += __shfl_xor(val, off, 32);
            f[j] = val;
        }
        if (s == 0) {
            float br = brep[0];
#pragma unroll
            for (int j = 0; j < 6; ++j) xt[(size_t)v * 6 + j] = f[j] + br;
        }
    } else if (bid < EB + CB) {
        // ----------------- count: degree histogram -----------------
        int i = (bid - EB) * 256 + t;
        if (i < e) {
            int ss = src[i], dd = dst[i];
            if (ss != dd) atomicAdd(&deg[dd], 1);
        }
    } else {
        // ----------------- xw1: 16 nodes per block -----------------
        float* shW = smem;                         // 4096 floats
        float* shX = smem + 4096;                  // 256 floats
        int xb = bid - EB - CB;
        int wv = t >> 6, l = t & 63;
#pragma unroll
        for (int i = 0; i < 16; ++i) shW[i * 256 + t] = W1[i * 256 + t];
        int h = l >> 3, c = l & 7;
        float a_i = att1[h * 16 + c];
        __syncthreads();

#pragma unroll
        for (int it = 0; it < 4; ++it) {
            int v = xb * 16 + it * 4 + wv;
            shX[wv * 64 + l] = x[(size_t)v * 64 + l];
            __builtin_amdgcn_wave_barrier();
            float acc = 0.f;
#pragma unroll
            for (int k4 = 0; k4 < 16; ++k4) {
                float4 xb4 = *(const float4*)&shX[wv * 64 + k4 * 4];
                acc += xb4.x * shW[(k4 * 4 + 0) * 64 + l];
                acc += xb4.y * shW[(k4 * 4 + 1) * 64 + l];
                acc += xb4.z * shW[(k4 * 4 + 2) * 64 + l];
                acc += xb4.w * shW[(k4 * 4 + 3) * 64 + l];
            }
            xwb[(size_t)v * 64 + l] = __float2bfloat16(acc);

            float pi = acc * a_i;
#pragma unroll
            for (int off = 1; off < 8; off <<= 1)
                pi += __shfl_xor(pi, off, 64);
            if (c == 0) ai[(size_t)v * 8 + h] = pi;
            __builtin_amdgcn_wave_barrier();
        }
    }
}

// ---------------------------------------------------------------------------
// scan: exclusive prefix over degrees (single block, 1024 threads)
// ---------------------------------------------------------------------------
__global__ void __launch_bounds__(1024) scan_kernel(
    const int* __restrict__ deg, int* __restrict__ offsets, int n)
{
    __shared__ int sums[1024];
    int t = threadIdx.x;
    int ch = (n + 1023) >> 10;
    int start = t * ch;
    int end = min(start + ch, n);
    int local = 0;
    for (int i = start; i < end; ++i) local += deg[i];
    sums[t] = local;
    __syncthreads();
    for (int off = 1; off < 1024; off <<= 1) {
        int val = (t >= off) ? sums[t - off] : 0;
        __syncthreads();
        sums[t] += val;
        __syncthreads();
    }
    int run = sums[t] - local;  // exclusive prefix
    for (int i = start; i < end; ++i) { offsets[i] = run; run += deg[i]; }
}

__global__ void scatter_kernel(const int* __restrict__ src, const int* __restrict__ dst,
                               const int* __restrict__ offsets, int* __restrict__ cursor,
                               int* __restrict__ elist, int e)
{
    int i = blockIdx.x * blockDim.x + threadIdx.x;
    if (i < e) {
        int s = src[i], d = dst[i];
        if (s != d) {
            int pos = offsets[d] + atomicAdd(&cursor[d], 1);
            elist[pos] = s;
        }
    }
}

// ---------------------------------------------------------------------------
// Fused GAT-1 aggregation + ELU + xw2 + layer-2 dots. ONE node per wave.
// Per edge: ONE gather (the bf16 row = one 128B line); aj1 recomputed from
// the gathered row via 3 shfl_xor (head = 8 contiguous lanes).
// Output: packed xw2 rows [80 bf16 cols | 8 bf16 aj2 | pad] stride 128.
// ---------------------------------------------------------------------------
__global__ void __launch_bounds__(256) agg1_fused_kernel(
    const __hip_bfloat16* __restrict__ xwb, const float* __restrict__ ai1,
    const float* __restrict__ b1,
    const float* __restrict__ xt, const float* __restrict__ W2,
    const float* __restrict__ att1, const float* __restrict__ att2,
    const int* __restrict__ offs, const int* __restrict__ deg,
    const int* __restrict__ elist,
    __hip_bfloat16* __restrict__ xw2p,
    float* __restrict__ ai2,
    int n)
{
    __shared__ float shW2[5600];
    __shared__ float shH[4][72];   // 64 h1 + 6 xt, per wave
    __shared__ float shR[4][80];   // xw2 row, per wave
    int t = threadIdx.x, wv = t >> 6, l = t & 63;
    for (int i = t; i < 5600; i += 256) shW2[i] = W2[i];
    __syncthreads();

    int h = l >> 3, c = l & 7;
    float attj_l = att1[h * 16 + 8 + c];   // a_j[h][c]
    int v = blockIdx.x * 4 + wv;
    float ai_l = ai1[(size_t)v * 8 + h];

    // self loop: aj recomputed from own bf16 row (consistent with edge path)
    float yself = __bfloat162float(xwb[(size_t)v * 64 + l]);
    float ps = yself * attj_l;
    ps += __shfl_xor(ps, 1, 64);
    ps += __shfl_xor(ps, 2, 64);
    ps += __shfl_xor(ps, 4, 64);
    float a = ai_l + ps;
    a = a >= 0.f ? a : NEG_SLOPE * a;
    float ea  = __expf(a);
    float acc = ea * yself;
    float den = ea;

    int off = offs[v], dg = deg[v];
    for (int j = 0; j < dg; j += 16) {
        int idxv = 0;
        if (l < 16 && j + l < dg) idxv = elist[off + j + l];
#pragma unroll
        for (int b = 0; b < 16; ++b) {
            int s = __shfl(idxv, b, 64);
            float y = __bfloat162float(xwb[(size_t)s * 64 + l]);
            float pp = y * attj_l;
            pp += __shfl_xor(pp, 1, 64);
            pp += __shfl_xor(pp, 2, 64);
            pp += __shfl_xor(pp, 4, 64);     // all 8 lanes of head h: aj1[s][h]
            float aa = ai_l + pp;
            aa = aa >= 0.f ? aa : NEG_SLOPE * aa;
            float w = (j + b < dg) ? __expf(aa) : 0.f;  // scalar condition
            acc += w * y;
            den += w;
        }
    }

    float o = acc / den + b1[l];
    o = o > 0.f ? o : expm1f(o);   // elu -> h1[v][l], stays on chip

    shH[wv][l] = o;
    if (l < 6) shH[wv][64 + l] = xt[(size_t)v * 6 + l];
    __builtin_amdgcn_wave_barrier();

    // xw2 row = concat(h1, xt) @ W2 ; lane l -> cols l and (l<16) 64+l
    float a0 = 0.f, a1 = 0.f;
#pragma unroll
    for (int kk = 0; kk < 70; ++kk) {
        float f = shH[wv][kk];
        a0 += f * shW2[kk * 80 + l];
        if (l < 16) a1 += f * shW2[kk * 80 + 64 + l];
    }
    __hip_bfloat16* row = xw2p + (size_t)v * 128;
    row[l] = __float2bfloat16(a0);
    shR[wv][l] = a0;
    if (l < 16) {
        row[64 + l] = __float2bfloat16(a1);
        shR[wv][64 + l] = a1;
    }
    __builtin_amdgcn_wave_barrier();

    if (l < 16) {
        int hh = l >> 1, wj = l & 1;
        float sdot = 0.f;
#pragma unroll
        for (int cc = 0; cc < 10; ++cc)
            sdot += shR[wv][hh * 10 + cc] * att2[hh * 20 + wj * 10 + cc];
        if (wj == 0) ai2[(size_t)v * 8 + hh] = sdot;
        else         row[80 + hh] = __float2bfloat16(sdot);  // aj2 packed
    }
}

// ---------------------------------------------------------------------------
// GAT layer 2 aggregation on packed rows + head-mean + b2 + log_softmax.
// One node per wave. Per edge: ONE u32 gather (lane l<44, 2 bf16 each:
// cols 2l,2l+1 for l<40; aj pairs for 40..43) = 2 lines; aj via 1 shfl.
// ---------------------------------------------------------------------------
__global__ void __launch_bounds__(256) agg2_kernel(
    const unsigned* __restrict__ xw2p, const float* __restrict__ ai2,
    const float* __restrict__ b2,
    const int* __restrict__ offs, const int* __restrict__ deg,
    const int* __restrict__ elist, float* __restrict__ out, int n)
{
    __shared__ float buf[4][80];
    __shared__ float buf2[4][10];
    int t = threadIdx.x, wv = t >> 6, l = t & 63;
    int v = blockIdx.x * 4 + wv;

    bool act = l < 44;
    int hc = (l < 40) ? (l / 5) : 0;       // head of cols (2l, 2l+1)
    int ajl = 40 + (hc >> 1);              // holder lane of aj pair
    float ai_l = (l < 40) ? ai2[(size_t)v * 8 + hc] : 0.f;

    // self loop (row base in u32: v*64 + l)
    unsigned selfw = 0;
    if (act) selfw = xw2p[(size_t)v * 64 + l];
    unsigned ajw = __shfl(selfw, ajl, 64);
    float ajs = (hc & 1) ? bf_hi(ajw) : bf_lo(ajw);
    float a = ai_l + ajs;
    a = a >= 0.f ? a : NEG_SLOPE * a;
    float e0 = __expf(a);
    float acc0 = e0 * bf_lo(selfw), acc1 = e0 * bf_hi(selfw), den = e0;

    int off = offs[v], dg = deg[v];
    for (int j = 0; j < dg; j += 16) {
        int idxv = 0;
        if (l < 16 && j + l < dg) idxv = elist[off + j + l];
#pragma unroll
        for (int b = 0; b < 16; ++b) {
            int s = __shfl(idxv, b, 64);
            unsigned yw = 0;
            if (act) yw = xw2p[(size_t)s * 64 + l];
            unsigned aw = __shfl(yw, ajl, 64);
            float aj = (hc & 1) ? bf_hi(aw) : bf_lo(aw);
            float u = ai_l + aj;
            u = u >= 0.f ? u : NEG_SLOPE * u;
            float w = (j + b < dg) ? __expf(u) : 0.f;   // scalar condition
            acc0 += w * bf_lo(yw);
            acc1 += w * bf_hi(yw);
            den += w;
        }
    }

    if (l < 40) {
        float inv = 1.f / den;
        buf[wv][2 * l]     = acc0 * inv;
        buf[wv][2 * l + 1] = acc1 * inv;
    }
    __builtin_amdgcn_wave_barrier();
    if (l < 10) {
        float mval = 0.f;
#pragma unroll
        for (int hh = 0; hh < 8; ++hh) mval += buf[wv][hh * 10 + l];
        buf2[wv][l] = mval * 0.125f + b2[l];
    }
    __builtin_amdgcn_wave_barrier();
    if (l < 10) {
        float mx = -1e30f;
#pragma unroll
        for (int cc = 0; cc < 10; ++cc) mx = fmaxf(mx, buf2[wv][cc]);
        float se = 0.f;
#pragma unroll
        for (int cc = 0; cc < 10; ++cc) se += __expf(buf2[wv][cc] - mx);
        out[(size_t)v * 10 + l] = buf2[wv][l] - mx - __logf(se);
    }
}

// ---------------------------------------------------------------------------
extern "C" void kernel_launch(void* const* d_in, const int* in_sizes, int n_in,
                              void* d_out, int out_size, void* d_ws, size_t ws_size,
                              hipStream_t stream)
{
    const float* x    = (const float*)d_in[0];
    const int*   ei   = (const int*)  d_in[1];
    const float* ef   = (const float*)d_in[2];
    const float* W1   = (const float*)d_in[3];
    const float* att1 = (const float*)d_in[4];
    const float* b1   = (const float*)d_in[5];
    const float* W2   = (const float*)d_in[6];
    const float* att2 = (const float*)d_in[7];
    const float* b2   = (const float*)d_in[8];
    const float* Wq   = (const float*)d_in[9];
    const float* bq   = (const float*)d_in[10];
    const float* Wk   = (const float*)d_in[11];
    const float* bk   = (const float*)d_in[12];
    const float* Wv   = (const float*)d_in[13];
    const float* bv   = (const float*)d_in[14];
    const float* g0   = (const float*)d_in[15];
    const float* be0  = (const float*)d_in[16];
    const float* Wf1  = (const float*)d_in[17];
    const float* bf1  = (const float*)d_in[18];
    const float* Wf2  = (const float*)d_in[19];
    const float* bf2  = (const float*)d_in[20];
    const float* g1   = (const float*)d_in[21];
    const float* be1  = (const float*)d_in[22];
    const float* Wrep = (const float*)d_in[23];
    const float* brep = (const float*)d_in[24];

    const int n = in_sizes[0] / 64;   // 100000
    const int e = in_sizes[1] / 2;    // 1600000
    const int* src = ei;
    const int* dst = ei + e;

    char* ws = (char*)d_ws;
    size_t o = 0;
    auto alloc = [&](size_t bytes) -> void* {
        void* p = ws + o;
        o += (bytes + 255) & ~(size_t)255;
        return p;
    };
    __hip_bfloat16* xw1b = (__hip_bfloat16*)alloc((size_t)n * 64 * 2);
    __hip_bfloat16* xw2p = (__hip_bfloat16*)alloc((size_t)n * 128 * 2); // packed
    float* ai1   = (float*)alloc((size_t)n * 8 * 4);
    float* ai2   = (float*)alloc((size_t)n * 8 * 4);
    float* xt    = (float*)alloc((size_t)n * 6 * 4);
    int*   deg   = (int*)  alloc((size_t)n * 4);
    int*   offs  = (int*)  alloc((size_t)n * 4);
    int*   cur   = (int*)  alloc((size_t)n * 4);
    int*   elist = (int*)  alloc((size_t)e * 4);
    (void)ws_size; (void)n_in; (void)out_size;

    hipMemsetAsync(deg, 0, (size_t)n * 4, stream);
    hipMemsetAsync(cur, 0, (size_t)n * 4, stream);

    const int EB = n / 8;                // 12500 encoder blocks
    const int CB = (e + 255) / 256;      // 6250 count blocks
    const int XB = n / 16;               // 6250 xw1 blocks
    front_kernel<<<EB + CB + XB, 256, 0, stream>>>(
        ef, Wq, bq, Wk, bk, Wv, bv, g0, be0, Wf1, bf1, Wf2, bf2, g1, be1,
        Wrep, brep, xt,
        src, dst, deg, e,
        x, W1, att1, xw1b, ai1,
        n, EB, CB);
    scan_kernel<<<1, 1024, 0, stream>>>(deg, offs, n);
    scatter_kernel<<<(e + 255) / 256, 256, 0, stream>>>(src, dst, offs, cur, elist, e);
    agg1_fused_kernel<<<n / 4, 256, 0, stream>>>(xw1b, ai1, b1, xt, W2, att1, att2,
                                                 offs, deg, elist, xw2p, ai2, n);
    agg2_kernel<<<n / 4, 256, 0, stream>>>((const unsigned*)xw2p, ai2, b2,
                                           offs, deg, elist, (float*)d_out, n);
}

// Round 8
// 895.476 us; speedup vs baseline: 1.3037x; 1.1726x over previous
//
#include <hip/hip_runtime.h>
#include <hip/hip_bf16.h>

// N=100000, E=1600000.
// Split pipeline (one kernel per stage) to expose per-stage timings.
// agg1: 1 line/edge (aj recomputed from gathered row). agg2: packed rows.

#define NEG_SLOPE 0.2f

__device__ __forceinline__ float bf_lo(unsigned u) { return __uint_as_float(u << 16); }
__device__ __forceinline__ float bf_hi(unsigned u) { return __uint_as_float(u & 0xffff0000u); }

// ---------------------------------------------------------------------------
// Encoder: per-node transformer, 8 nodes/block, 32 lanes/node, LDS K/V slab.
// ---------------------------------------------------------------------------
__global__ void __launch_bounds__(256) encoder_kernel(
    const float* __restrict__ Xf,
    const float* __restrict__ Wq, const float* __restrict__ bq,
    const float* __restrict__ Wk, const float* __restrict__ bk,
    const float* __restrict__ Wv, const float* __restrict__ bv,
    const float* __restrict__ g0, const float* __restrict__ be0,
    const float* __restrict__ Wf1, const float* __restrict__ bf1,
    const float* __restrict__ Wf2, const float* __restrict__ bf2,
    const float* __restrict__ g1, const float* __restrict__ be1,
    const float* __restrict__ Wrep, const float* __restrict__ brep,
    float* __restrict__ xt, int n)
{
    __shared__ float sh[4096];
    int t = threadIdx.x;
    int bid = blockIdx.x;
    size_t base = (size_t)bid * 2560;
#pragma unroll
    for (int i = 0; i < 10; ++i) sh[i * 256 + t] = Xf[base + i * 256 + t];
    __syncthreads();

    int sub = t >> 5;
    int s   = t & 31;
    int v   = bid * 8 + sub;

    float xv[10];
#pragma unroll
    for (int i = 0; i < 10; ++i) xv[i] = sh[sub * 320 + s * 10 + i];
    __syncthreads();   // Xf consumed; slab reused for K/V

    float q[6], k[6], w[6];
#pragma unroll
    for (int j = 0; j < 6; ++j) { q[j] = bq[j]; k[j] = bk[j]; w[j] = bv[j]; }
#pragma unroll
    for (int i = 0; i < 10; ++i) {
#pragma unroll
        for (int j = 0; j < 6; ++j) {
            q[j] += xv[i] * Wq[i * 6 + j];
            k[j] += xv[i] * Wk[i * 6 + j];
            w[j] += xv[i] * Wv[i * 6 + j];
        }
    }

    // K/V slab: per node [2 heads][32 tokens][8 floats]; same-wave only.
    int kvb = sub * 512 + s * 8;
    *(float4*)&sh[kvb      ] = make_float4(k[0], k[1], k[2], 0.f);
    *(float4*)&sh[kvb +   4] = make_float4(w[0], w[1], w[2], 0.f);
    *(float4*)&sh[kvb + 256] = make_float4(k[3], k[4], k[5], 0.f);
    *(float4*)&sh[kvb + 260] = make_float4(w[3], w[4], w[5], 0.f);
    __builtin_amdgcn_wave_barrier();

    const float scale = 0.40824829046386301637f;  // 1/sqrt(6)
    float O[6];
#pragma unroll
    for (int hh = 0; hh < 2; ++hh) {
        const float q0 = q[hh * 3 + 0] * scale;
        const float q1 = q[hh * 3 + 1] * scale;
        const float q2 = q[hh * 3 + 2] * scale;
        int kb = sub * 512 + hh * 256;
        float dA = 0.f, dB = 0.f;
        float aA0 = 0.f, aA1 = 0.f, aA2 = 0.f;
        float aB0 = 0.f, aB1 = 0.f, aB2 = 0.f;
#pragma unroll
        for (int t2 = 0; t2 < 32; t2 += 2) {
            float4 kk0 = *(const float4*)&sh[kb + t2 * 8];
            float4 vv0 = *(const float4*)&sh[kb + t2 * 8 + 4];
            float4 kk1 = *(const float4*)&sh[kb + t2 * 8 + 8];
            float4 vv1 = *(const float4*)&sh[kb + t2 * 8 + 12];
            float p0 = __expf(q0 * kk0.x + q1 * kk0.y + q2 * kk0.z);
            float p1 = __expf(q0 * kk1.x + q1 * kk1.y + q2 * kk1.z);
            dA += p0; aA0 += p0 * vv0.x; aA1 += p0 * vv0.y; aA2 += p0 * vv0.z;
            dB += p1; aB0 += p1 * vv1.x; aB1 += p1 * vv1.y; aB2 += p1 * vv1.z;
        }
        float inv = 1.f / (dA + dB);
        O[hh * 3 + 0] = q[hh * 3 + 0] + (aA0 + aB0) * inv;
        O[hh * 3 + 1] = q[hh * 3 + 1] + (aA1 + aB1) * inv;
        O[hh * 3 + 2] = q[hh * 3 + 2] + (aA2 + aB2) * inv;
    }

    {
        float mean = (O[0] + O[1] + O[2] + O[3] + O[4] + O[5]) * (1.f / 6.f);
        float var = 0.f;
#pragma unroll
        for (int j = 0; j < 6; ++j) { float d = O[j] - mean; var += d * d; }
        var *= (1.f / 6.f);
        float r = 1.f / sqrtf(var + 1e-5f);
#pragma unroll
        for (int j = 0; j < 6; ++j) O[j] = (O[j] - mean) * r * g0[j] + be0[j];
    }

    float f[6];
    {
        float hbuf[24];
#pragma unroll
        for (int r = 0; r < 24; ++r) {
            float tt = bf1[r];
#pragma unroll
            for (int j = 0; j < 6; ++j) tt += O[j] * Wf1[j * 24 + r];
            hbuf[r] = fmaxf(tt, 0.f);
        }
#pragma unroll
        for (int j = 0; j < 6; ++j) {
            float tt = bf2[j];
#pragma unroll
            for (int r = 0; r < 24; ++r) tt += hbuf[r] * Wf2[r * 6 + j];
            f[j] = O[j] + tt;
        }
    }
    {
        float mean = (f[0] + f[1] + f[2] + f[3] + f[4] + f[5]) * (1.f / 6.f);
        float var = 0.f;
#pragma unroll
        for (int j = 0; j < 6; ++j) { float d = f[j] - mean; var += d * d; }
        var *= (1.f / 6.f);
        float r = 1.f / sqrtf(var + 1e-5f);
#pragma unroll
        for (int j = 0; j < 6; ++j) f[j] = (f[j] - mean) * r * g1[j] + be1[j];
    }

    float wr = Wrep[s];
#pragma unroll
    for (int j = 0; j < 6; ++j) {
        float val = f[j] * wr;
#pragma unroll
        for (int off = 16; off >= 1; off >>= 1) val += __shfl_xor(val, off, 32);
        f[j] = val;
    }
    if (s == 0) {
        float br = brep[0];
#pragma unroll
        for (int j = 0; j < 6; ++j) xt[(size_t)v * 6 + j] = f[j] + br;
    }
}

// ---------------------------------------------------------------------------
// xw1 = x @ W1 -> bf16 table (N,64); ai1 fp32 dots (N,8). 16 nodes/block.
// ---------------------------------------------------------------------------
__global__ void __launch_bounds__(256) xw1_kernel(
    const float* __restrict__ x, const float* __restrict__ W1,
    const float* __restrict__ att1,
    __hip_bfloat16* __restrict__ xwb,
    float* __restrict__ ai, int n)
{
    __shared__ float shW[4096];
    __shared__ float shX[256];
    int t = threadIdx.x, wv = t >> 6, l = t & 63;
#pragma unroll
    for (int i = 0; i < 16; ++i) shW[i * 256 + t] = W1[i * 256 + t];
    int h = l >> 3, c = l & 7;
    float a_i = att1[h * 16 + c];
    __syncthreads();

#pragma unroll
    for (int it = 0; it < 4; ++it) {
        int v = blockIdx.x * 16 + it * 4 + wv;
        shX[wv * 64 + l] = x[(size_t)v * 64 + l];
        __builtin_amdgcn_wave_barrier();
        float acc = 0.f;
#pragma unroll
        for (int k4 = 0; k4 < 16; ++k4) {
            float4 xb4 = *(const float4*)&shX[wv * 64 + k4 * 4];
            acc += xb4.x * shW[(k4 * 4 + 0) * 64 + l];
            acc += xb4.y * shW[(k4 * 4 + 1) * 64 + l];
            acc += xb4.z * shW[(k4 * 4 + 2) * 64 + l];
            acc += xb4.w * shW[(k4 * 4 + 3) * 64 + l];
        }
        xwb[(size_t)v * 64 + l] = __float2bfloat16(acc);

        float pi = acc * a_i;
#pragma unroll
        for (int off = 1; off < 8; off <<= 1)
            pi += __shfl_xor(pi, off, 64);
        if (c == 0) ai[(size_t)v * 8 + h] = pi;
        __builtin_amdgcn_wave_barrier();
    }
}

// ---------------------------------------------------------------------------
// CSR build: count -> 3-kernel scan -> scatter
// ---------------------------------------------------------------------------
__global__ void count_kernel(const int* __restrict__ src, const int* __restrict__ dst,
                             int* __restrict__ deg, int e)
{
    int i = blockIdx.x * blockDim.x + threadIdx.x;
    if (i < e) {
        int s = src[i], d = dst[i];
        if (s != d) atomicAdd(&deg[d], 1);
    }
}

__global__ void __launch_bounds__(1024) scan1_kernel(
    const int* __restrict__ deg, int* __restrict__ bsum, int n)
{
    __shared__ int sh[1024];
    int t = threadIdx.x;
    int i = blockIdx.x * 1024 + t;
    sh[t] = (i < n) ? deg[i] : 0;
    __syncthreads();
    for (int off = 512; off >= 1; off >>= 1) {
        if (t < off) sh[t] += sh[t + off];
        __syncthreads();
    }
    if (t == 0) bsum[blockIdx.x] = sh[0];
}

__global__ void __launch_bounds__(128) scan2_kernel(int* __restrict__ bsum, int nb)
{
    __shared__ int sh[128];
    int t = threadIdx.x;
    int v = (t < nb) ? bsum[t] : 0;
    sh[t] = v;
    __syncthreads();
    for (int off = 1; off < 128; off <<= 1) {
        int val = (t >= off) ? sh[t - off] : 0;
        __syncthreads();
        sh[t] += val;
        __syncthreads();
    }
    if (t < nb) bsum[t] = sh[t] - v;   // exclusive
}

__global__ void __launch_bounds__(1024) scan3_kernel(
    const int* __restrict__ deg, const int* __restrict__ bsum,
    int* __restrict__ offs, int n)
{
    __shared__ int sh[1024];
    int t = threadIdx.x;
    int i = blockIdx.x * 1024 + t;
    int v = (i < n) ? deg[i] : 0;
    sh[t] = v;
    __syncthreads();
    for (int off = 1; off < 1024; off <<= 1) {
        int val = (t >= off) ? sh[t - off] : 0;
        __syncthreads();
        sh[t] += val;
        __syncthreads();
    }
    if (i < n) offs[i] = bsum[blockIdx.x] + sh[t] - v;
}

__global__ void scatter_kernel(const int* __restrict__ src, const int* __restrict__ dst,
                               const int* __restrict__ offsets, int* __restrict__ cursor,
                               int* __restrict__ elist, int e)
{
    int i = blockIdx.x * blockDim.x + threadIdx.x;
    if (i < e) {
        int s = src[i], d = dst[i];
        if (s != d) {
            int pos = offsets[d] + atomicAdd(&cursor[d], 1);
            elist[pos] = s;
        }
    }
}

// ---------------------------------------------------------------------------
// Fused GAT-1 aggregation + ELU + xw2 + layer-2 dots. ONE node per wave.
// Per edge: ONE gather (bf16 row = one 128B line); aj1 recomputed via shfl.
// Output: packed xw2 rows [80 bf16 | 8 bf16 aj2 | pad] stride 128 u16.
// ---------------------------------------------------------------------------
__global__ void __launch_bounds__(256) agg1_fused_kernel(
    const __hip_bfloat16* __restrict__ xwb, const float* __restrict__ ai1,
    const float* __restrict__ b1,
    const float* __restrict__ xt, const float* __restrict__ W2,
    const float* __restrict__ att1, const float* __restrict__ att2,
    const int* __restrict__ offs, const int* __restrict__ deg,
    const int* __restrict__ elist,
    __hip_bfloat16* __restrict__ xw2p,
    float* __restrict__ ai2,
    int n)
{
    __shared__ float shW2[5600];
    __shared__ float shH[4][72];   // 64 h1 + 6 xt, per wave
    __shared__ float shR[4][80];   // xw2 row, per wave
    int t = threadIdx.x, wv = t >> 6, l = t & 63;
    for (int i = t; i < 5600; i += 256) shW2[i] = W2[i];
    __syncthreads();

    int h = l >> 3, c = l & 7;
    float attj_l = att1[h * 16 + 8 + c];   // a_j[h][c]
    int v = blockIdx.x * 4 + wv;
    float ai_l = ai1[(size_t)v * 8 + h];

    // self loop: aj recomputed from own bf16 row (consistent with edge path)
    float yself = __bfloat162float(xwb[(size_t)v * 64 + l]);
    float ps = yself * attj_l;
    ps += __shfl_xor(ps, 1, 64);
    ps += __shfl_xor(ps, 2, 64);
    ps += __shfl_xor(ps, 4, 64);
    float a = ai_l + ps;
    a = a >= 0.f ? a : NEG_SLOPE * a;
    float ea  = __expf(a);
    float acc = ea * yself;
    float den = ea;

    int off = offs[v], dg = deg[v];
    for (int j = 0; j < dg; j += 16) {
        int idxv = 0;
        if (l < 16 && j + l < dg) idxv = elist[off + j + l];
#pragma unroll
        for (int b = 0; b < 16; ++b) {
            int s = __shfl(idxv, b, 64);
            float y = __bfloat162float(xwb[(size_t)s * 64 + l]);
            float pp = y * attj_l;
            pp += __shfl_xor(pp, 1, 64);
            pp += __shfl_xor(pp, 2, 64);
            pp += __shfl_xor(pp, 4, 64);     // aj1[s][h] on all 8 lanes of head
            float aa = ai_l + pp;
            aa = aa >= 0.f ? aa : NEG_SLOPE * aa;
            float w = (j + b < dg) ? __expf(aa) : 0.f;  // scalar condition
            acc += w * y;
            den += w;
        }
    }

    float o = acc / den + b1[l];
    o = o > 0.f ? o : expm1f(o);   // elu -> h1[v][l], stays on chip

    shH[wv][l] = o;
    if (l < 6) shH[wv][64 + l] = xt[(size_t)v * 6 + l];
    __builtin_amdgcn_wave_barrier();

    // xw2 row = concat(h1, xt) @ W2 ; lane l -> cols l and (l<16) 64+l
    float a0 = 0.f, a1 = 0.f;
#pragma unroll
    for (int kk = 0; kk < 70; ++kk) {
        float f = shH[wv][kk];
        a0 += f * shW2[kk * 80 + l];
        if (l < 16) a1 += f * shW2[kk * 80 + 64 + l];
    }
    __hip_bfloat16* row = xw2p + (size_t)v * 128;
    row[l] = __float2bfloat16(a0);
    shR[wv][l] = a0;
    if (l < 16) {
        row[64 + l] = __float2bfloat16(a1);
        shR[wv][64 + l] = a1;
    }
    __builtin_amdgcn_wave_barrier();

    if (l < 16) {
        int hh = l >> 1, wj = l & 1;
        float sdot = 0.f;
#pragma unroll
        for (int cc = 0; cc < 10; ++cc)
            sdot += shR[wv][hh * 10 + cc] * att2[hh * 20 + wj * 10 + cc];
        if (wj == 0) ai2[(size_t)v * 8 + hh] = sdot;
        else         row[80 + hh] = __float2bfloat16(sdot);  // aj2 packed
    }
}

// ---------------------------------------------------------------------------
// GAT layer 2 aggregation on packed rows + head-mean + b2 + log_softmax.
// One node per wave; 1 u32 gather per edge (44 lanes, 2 lines) + 1 shfl.
// ---------------------------------------------------------------------------
__global__ void __launch_bounds__(256) agg2_kernel(
    const unsigned* __restrict__ xw2p, const float* __restrict__ ai2,
    const float* __restrict__ b2,
    const int* __restrict__ offs, const int* __restrict__ deg,
    const int* __restrict__ elist, float* __restrict__ out, int n)
{
    __shared__ float buf[4][80];
    __shared__ float buf2[4][10];
    int t = threadIdx.x, wv = t >> 6, l = t & 63;
    int v = blockIdx.x * 4 + wv;

    bool act = l < 44;
    int hc = (l < 40) ? (l / 5) : 0;       // head of cols (2l, 2l+1)
    int ajl = 40 + (hc >> 1);              // holder lane of aj pair
    float ai_l = (l < 40) ? ai2[(size_t)v * 8 + hc] : 0.f;

    unsigned selfw = 0;
    if (act) selfw = xw2p[(size_t)v * 64 + l];
    unsigned ajw = __shfl(selfw, ajl, 64);
    float ajs = (hc & 1) ? bf_hi(ajw) : bf_lo(ajw);
    float a = ai_l + ajs;
    a = a >= 0.f ? a : NEG_SLOPE * a;
    float e0 = __expf(a);
    float acc0 = e0 * bf_lo(selfw), acc1 = e0 * bf_hi(selfw), den = e0;

    int off = offs[v], dg = deg[v];
    for (int j = 0; j < dg; j += 16) {
        int idxv = 0;
        if (l < 16 && j + l < dg) idxv = elist[off + j + l];
#pragma unroll
        for (int b = 0; b < 16; ++b) {
            int s = __shfl(idxv, b, 64);
            unsigned yw = 0;
            if (act) yw = xw2p[(size_t)s * 64 + l];
            unsigned aw = __shfl(yw, ajl, 64);
            float aj = (hc & 1) ? bf_hi(aw) : bf_lo(aw);
            float u = ai_l + aj;
            u = u >= 0.f ? u : NEG_SLOPE * u;
            float w = (j + b < dg) ? __expf(u) : 0.f;   // scalar condition
            acc0 += w * bf_lo(yw);
            acc1 += w * bf_hi(yw);
            den += w;
        }
    }

    if (l < 40) {
        float inv = 1.f / den;
        buf[wv][2 * l]     = acc0 * inv;
        buf[wv][2 * l + 1] = acc1 * inv;
    }
    __builtin_amdgcn_wave_barrier();
    if (l < 10) {
        float mval = 0.f;
#pragma unroll
        for (int hh = 0; hh < 8; ++hh) mval += buf[wv][hh * 10 + l];
        buf2[wv][l] = mval * 0.125f + b2[l];
    }
    __builtin_amdgcn_wave_barrier();
    if (l < 10) {
        float mx = -1e30f;
#pragma unroll
        for (int cc = 0; cc < 10; ++cc) mx = fmaxf(mx, buf2[wv][cc]);
        float se = 0.f;
#pragma unroll
        for (int cc = 0; cc < 10; ++cc) se += __expf(buf2[wv][cc] - mx);
        out[(size_t)v * 10 + l] = buf2[wv][l] - mx - __logf(se);
    }
}

// ---------------------------------------------------------------------------
extern "C" void kernel_launch(void* const* d_in, const int* in_sizes, int n_in,
                              void* d_out, int out_size, void* d_ws, size_t ws_size,
                              hipStream_t stream)
{
    const float* x    = (const float*)d_in[0];
    const int*   ei   = (const int*)  d_in[1];
    const float* ef   = (const float*)d_in[2];
    const float* W1   = (const float*)d_in[3];
    const float* att1 = (const float*)d_in[4];
    const float* b1   = (const float*)d_in[5];
    const float* W2   = (const float*)d_in[6];
    const float* att2 = (const float*)d_in[7];
    const float* b2   = (const float*)d_in[8];
    const float* Wq   = (const float*)d_in[9];
    const float* bq   = (const float*)d_in[10];
    const float* Wk   = (const float*)d_in[11];
    const float* bk   = (const float*)d_in[12];
    const float* Wv   = (const float*)d_in[13];
    const float* bv   = (const float*)d_in[14];
    const float* g0   = (const float*)d_in[15];
    const float* be0  = (const float*)d_in[16];
    const float* Wf1  = (const float*)d_in[17];
    const float* bf1  = (const float*)d_in[18];
    const float* Wf2  = (const float*)d_in[19];
    const float* bf2  = (const float*)d_in[20];
    const float* g1   = (const float*)d_in[21];
    const float* be1  = (const float*)d_in[22];
    const float* Wrep = (const float*)d_in[23];
    const float* brep = (const float*)d_in[24];

    const int n = in_sizes[0] / 64;   // 100000
    const int e = in_sizes[1] / 2;    // 1600000
    const int* src = ei;
    const int* dst = ei + e;

    char* ws = (char*)d_ws;
    size_t o = 0;
    auto alloc = [&](size_t bytes) -> void* {
        void* p = ws + o;
        o += (bytes + 255) & ~(size_t)255;
        return p;
    };
    __hip_bfloat16* xw1b = (__hip_bfloat16*)alloc((size_t)n * 64 * 2);
    __hip_bfloat16* xw2p = (__hip_bfloat16*)alloc((size_t)n * 128 * 2); // packed
    float* ai1   = (float*)alloc((size_t)n * 8 * 4);
    float* ai2   = (float*)alloc((size_t)n * 8 * 4);
    float* xt    = (float*)alloc((size_t)n * 6 * 4);
    int*   deg   = (int*)  alloc((size_t)n * 4);
    int*   offs  = (int*)  alloc((size_t)n * 4);
    int*   cur   = (int*)  alloc((size_t)n * 4);
    int*   bsum  = (int*)  alloc(256 * 4);
    int*   elist = (int*)  alloc((size_t)e * 4);
    (void)ws_size; (void)n_in; (void)out_size;

    hipMemsetAsync(deg, 0, (size_t)n * 4, stream);
    hipMemsetAsync(cur, 0, (size_t)n * 4, stream);

    const int NB = (n + 1023) / 1024;    // 98 scan blocks

    count_kernel<<<(e + 255) / 256, 256, 0, stream>>>(src, dst, deg, e);
    encoder_kernel<<<n / 8, 256, 0, stream>>>(ef, Wq, bq, Wk, bk, Wv, bv, g0, be0,
                                              Wf1, bf1, Wf2, bf2, g1, be1, Wrep, brep,
                                              xt, n);
    xw1_kernel<<<n / 16, 256, 0, stream>>>(x, W1, att1, xw1b, ai1, n);
    scan1_kernel<<<NB, 1024, 0, stream>>>(deg, bsum, n);
    scan2_kernel<<<1, 128, 0, stream>>>(bsum, NB);
    scan3_kernel<<<NB, 1024, 0, stream>>>(deg, bsum, offs, n);
    scatter_kernel<<<(e + 255) / 256, 256, 0, stream>>>(src, dst, offs, cur, elist, e);
    agg1_fused_kernel<<<n / 4, 256, 0, stream>>>(xw1b, ai1, b1, xt, W2, att1, att2,
                                                 offs, deg, elist, xw2p, ai2, n);
    agg2_kernel<<<n / 4, 256, 0, stream>>>((const unsigned*)xw2p, ai2, b2,
                                           offs, deg, elist, (float*)d_out, n);
}

// Round 9
// 825.482 us; speedup vs baseline: 1.4142x; 1.0848x over previous
//
#include <hip/hip_runtime.h>
#include <hip/hip_bf16.h>

// N=100000, E=1600000.
// R9: agg1 unfused -> pure gather kernel (zero LDS, max occupancy) + separate
// xw2pack kernel (W2 staged once per 16 nodes). h1 round-trips as bf16.

#define NEG_SLOPE 0.2f

__device__ __forceinline__ float bf_lo(unsigned u) { return __uint_as_float(u << 16); }
__device__ __forceinline__ float bf_hi(unsigned u) { return __uint_as_float(u & 0xffff0000u); }

// ---------------------------------------------------------------------------
// Encoder: per-node transformer, 8 nodes/block, 32 lanes/node, LDS K/V slab.
// ---------------------------------------------------------------------------
__global__ void __launch_bounds__(256) encoder_kernel(
    const float* __restrict__ Xf,
    const float* __restrict__ Wq, const float* __restrict__ bq,
    const float* __restrict__ Wk, const float* __restrict__ bk,
    const float* __restrict__ Wv, const float* __restrict__ bv,
    const float* __restrict__ g0, const float* __restrict__ be0,
    const float* __restrict__ Wf1, const float* __restrict__ bf1,
    const float* __restrict__ Wf2, const float* __restrict__ bf2,
    const float* __restrict__ g1, const float* __restrict__ be1,
    const float* __restrict__ Wrep, const float* __restrict__ brep,
    float* __restrict__ xt, int n)
{
    __shared__ float sh[4096];
    int t = threadIdx.x;
    int bid = blockIdx.x;
    size_t base = (size_t)bid * 2560;
#pragma unroll
    for (int i = 0; i < 10; ++i) sh[i * 256 + t] = Xf[base + i * 256 + t];
    __syncthreads();

    int sub = t >> 5;
    int s   = t & 31;
    int v   = bid * 8 + sub;

    float xv[10];
#pragma unroll
    for (int i = 0; i < 10; ++i) xv[i] = sh[sub * 320 + s * 10 + i];
    __syncthreads();   // Xf consumed; slab reused for K/V

    float q[6], k[6], w[6];
#pragma unroll
    for (int j = 0; j < 6; ++j) { q[j] = bq[j]; k[j] = bk[j]; w[j] = bv[j]; }
#pragma unroll
    for (int i = 0; i < 10; ++i) {
#pragma unroll
        for (int j = 0; j < 6; ++j) {
            q[j] += xv[i] * Wq[i * 6 + j];
            k[j] += xv[i] * Wk[i * 6 + j];
            w[j] += xv[i] * Wv[i * 6 + j];
        }
    }

    // K/V slab: per node [2 heads][32 tokens][8 floats]; same-wave only.
    int kvb = sub * 512 + s * 8;
    *(float4*)&sh[kvb      ] = make_float4(k[0], k[1], k[2], 0.f);
    *(float4*)&sh[kvb +   4] = make_float4(w[0], w[1], w[2], 0.f);
    *(float4*)&sh[kvb + 256] = make_float4(k[3], k[4], k[5], 0.f);
    *(float4*)&sh[kvb + 260] = make_float4(w[3], w[4], w[5], 0.f);
    __builtin_amdgcn_wave_barrier();

    const float scale = 0.40824829046386301637f;  // 1/sqrt(6)
    float O[6];
#pragma unroll
    for (int hh = 0; hh < 2; ++hh) {
        const float q0 = q[hh * 3 + 0] * scale;
        const float q1 = q[hh * 3 + 1] * scale;
        const float q2 = q[hh * 3 + 2] * scale;
        int kb = sub * 512 + hh * 256;
        float dA = 0.f, dB = 0.f;
        float aA0 = 0.f, aA1 = 0.f, aA2 = 0.f;
        float aB0 = 0.f, aB1 = 0.f, aB2 = 0.f;
#pragma unroll
        for (int t2 = 0; t2 < 32; t2 += 2) {
            float4 kk0 = *(const float4*)&sh[kb + t2 * 8];
            float4 vv0 = *(const float4*)&sh[kb + t2 * 8 + 4];
            float4 kk1 = *(const float4*)&sh[kb + t2 * 8 + 8];
            float4 vv1 = *(const float4*)&sh[kb + t2 * 8 + 12];
            float p0 = __expf(q0 * kk0.x + q1 * kk0.y + q2 * kk0.z);
            float p1 = __expf(q0 * kk1.x + q1 * kk1.y + q2 * kk1.z);
            dA += p0; aA0 += p0 * vv0.x; aA1 += p0 * vv0.y; aA2 += p0 * vv0.z;
            dB += p1; aB0 += p1 * vv1.x; aB1 += p1 * vv1.y; aB2 += p1 * vv1.z;
        }
        float inv = 1.f / (dA + dB);
        O[hh * 3 + 0] = q[hh * 3 + 0] + (aA0 + aB0) * inv;
        O[hh * 3 + 1] = q[hh * 3 + 1] + (aA1 + aB1) * inv;
        O[hh * 3 + 2] = q[hh * 3 + 2] + (aA2 + aB2) * inv;
    }

    {
        float mean = (O[0] + O[1] + O[2] + O[3] + O[4] + O[5]) * (1.f / 6.f);
        float var = 0.f;
#pragma unroll
        for (int j = 0; j < 6; ++j) { float d = O[j] - mean; var += d * d; }
        var *= (1.f / 6.f);
        float r = 1.f / sqrtf(var + 1e-5f);
#pragma unroll
        for (int j = 0; j < 6; ++j) O[j] = (O[j] - mean) * r * g0[j] + be0[j];
    }

    float f[6];
    {
        float hbuf[24];
#pragma unroll
        for (int r = 0; r < 24; ++r) {
            float tt = bf1[r];
#pragma unroll
            for (int j = 0; j < 6; ++j) tt += O[j] * Wf1[j * 24 + r];
            hbuf[r] = fmaxf(tt, 0.f);
        }
#pragma unroll
        for (int j = 0; j < 6; ++j) {
            float tt = bf2[j];
#pragma unroll
            for (int r = 0; r < 24; ++r) tt += hbuf[r] * Wf2[r * 6 + j];
            f[j] = O[j] + tt;
        }
    }
    {
        float mean = (f[0] + f[1] + f[2] + f[3] + f[4] + f[5]) * (1.f / 6.f);
        float var = 0.f;
#pragma unroll
        for (int j = 0; j < 6; ++j) { float d = f[j] - mean; var += d * d; }
        var *= (1.f / 6.f);
        float r = 1.f / sqrtf(var + 1e-5f);
#pragma unroll
        for (int j = 0; j < 6; ++j) f[j] = (f[j] - mean) * r * g1[j] + be1[j];
    }

    float wr = Wrep[s];
#pragma unroll
    for (int j = 0; j < 6; ++j) {
        float val = f[j] * wr;
#pragma unroll
        for (int off = 16; off >= 1; off >>= 1) val += __shfl_xor(val, off, 32);
        f[j] = val;
    }
    if (s == 0) {
        float br = brep[0];
#pragma unroll
        for (int j = 0; j < 6; ++j) xt[(size_t)v * 6 + j] = f[j] + br;
    }
}

// ---------------------------------------------------------------------------
// xw1 = x @ W1 -> bf16 table (N,64); ai1 fp32 dots (N,8). 16 nodes/block.
// ---------------------------------------------------------------------------
__global__ void __launch_bounds__(256) xw1_kernel(
    const float* __restrict__ x, const float* __restrict__ W1,
    const float* __restrict__ att1,
    __hip_bfloat16* __restrict__ xwb,
    float* __restrict__ ai, int n)
{
    __shared__ float shW[4096];
    __shared__ float shX[256];
    int t = threadIdx.x, wv = t >> 6, l = t & 63;
#pragma unroll
    for (int i = 0; i < 16; ++i) shW[i * 256 + t] = W1[i * 256 + t];
    int h = l >> 3, c = l & 7;
    float a_i = att1[h * 16 + c];
    __syncthreads();

#pragma unroll
    for (int it = 0; it < 4; ++it) {
        int v = blockIdx.x * 16 + it * 4 + wv;
        shX[wv * 64 + l] = x[(size_t)v * 64 + l];
        __builtin_amdgcn_wave_barrier();
        float acc = 0.f;
#pragma unroll
        for (int k4 = 0; k4 < 16; ++k4) {
            float4 xb4 = *(const float4*)&shX[wv * 64 + k4 * 4];
            acc += xb4.x * shW[(k4 * 4 + 0) * 64 + l];
            acc += xb4.y * shW[(k4 * 4 + 1) * 64 + l];
            acc += xb4.z * shW[(k4 * 4 + 2) * 64 + l];
            acc += xb4.w * shW[(k4 * 4 + 3) * 64 + l];
        }
        xwb[(size_t)v * 64 + l] = __float2bfloat16(acc);

        float pi = acc * a_i;
#pragma unroll
        for (int off = 1; off < 8; off <<= 1)
            pi += __shfl_xor(pi, off, 64);
        if (c == 0) ai[(size_t)v * 8 + h] = pi;
        __builtin_amdgcn_wave_barrier();
    }
}

// ---------------------------------------------------------------------------
// CSR build: count -> 3-kernel scan -> scatter
// ---------------------------------------------------------------------------
__global__ void count_kernel(const int* __restrict__ src, const int* __restrict__ dst,
                             int* __restrict__ deg, int e)
{
    int i = blockIdx.x * blockDim.x + threadIdx.x;
    if (i < e) {
        int s = src[i], d = dst[i];
        if (s != d) atomicAdd(&deg[d], 1);
    }
}

__global__ void __launch_bounds__(1024) scan1_kernel(
    const int* __restrict__ deg, int* __restrict__ bsum, int n)
{
    __shared__ int sh[1024];
    int t = threadIdx.x;
    int i = blockIdx.x * 1024 + t;
    sh[t] = (i < n) ? deg[i] : 0;
    __syncthreads();
    for (int off = 512; off >= 1; off >>= 1) {
        if (t < off) sh[t] += sh[t + off];
        __syncthreads();
    }
    if (t == 0) bsum[blockIdx.x] = sh[0];
}

__global__ void __launch_bounds__(128) scan2_kernel(int* __restrict__ bsum, int nb)
{
    __shared__ int sh[128];
    int t = threadIdx.x;
    int v = (t < nb) ? bsum[t] : 0;
    sh[t] = v;
    __syncthreads();
    for (int off = 1; off < 128; off <<= 1) {
        int val = (t >= off) ? sh[t - off] : 0;
        __syncthreads();
        sh[t] += val;
        __syncthreads();
    }
    if (t < nb) bsum[t] = sh[t] - v;   // exclusive
}

__global__ void __launch_bounds__(1024) scan3_kernel(
    const int* __restrict__ deg, const int* __restrict__ bsum,
    int* __restrict__ offs, int n)
{
    __shared__ int sh[1024];
    int t = threadIdx.x;
    int i = blockIdx.x * 1024 + t;
    int v = (i < n) ? deg[i] : 0;
    sh[t] = v;
    __syncthreads();
    for (int off = 1; off < 1024; off <<= 1) {
        int val = (t >= off) ? sh[t - off] : 0;
        __syncthreads();
        sh[t] += val;
        __syncthreads();
    }
    if (i < n) offs[i] = bsum[blockIdx.x] + sh[t] - v;
}

__global__ void scatter_kernel(const int* __restrict__ src, const int* __restrict__ dst,
                               const int* __restrict__ offsets, int* __restrict__ cursor,
                               int* __restrict__ elist, int e)
{
    int i = blockIdx.x * blockDim.x + threadIdx.x;
    if (i < e) {
        int s = src[i], d = dst[i];
        if (s != d) {
            int pos = offsets[d] + atomicAdd(&cursor[d], 1);
            elist[pos] = s;
        }
    }
}

// ---------------------------------------------------------------------------
// PURE GAT-1 aggregation: ONE node per wave, ZERO LDS, no block barrier.
// Per edge: 1 row gather (128B line); aj1 recomputed via 3 shfl_xor.
// Writes h1 as bf16.
// ---------------------------------------------------------------------------
__global__ void __launch_bounds__(256) agg1_kernel(
    const __hip_bfloat16* __restrict__ xwb, const float* __restrict__ ai1,
    const float* __restrict__ att1, const float* __restrict__ b1,
    const int* __restrict__ offs, const int* __restrict__ deg,
    const int* __restrict__ elist,
    __hip_bfloat16* __restrict__ h1b, int n)
{
    int t = threadIdx.x, wv = t >> 6, l = t & 63;
    int v = blockIdx.x * 4 + wv;
    int h = l >> 3, c = l & 7;
    float attj_l = att1[h * 16 + 8 + c];   // a_j[h][c]
    float ai_l = ai1[(size_t)v * 8 + h];

    // self loop: aj recomputed from own bf16 row (consistent with edge path)
    float yself = __bfloat162float(xwb[(size_t)v * 64 + l]);
    float ps = yself * attj_l;
    ps += __shfl_xor(ps, 1, 64);
    ps += __shfl_xor(ps, 2, 64);
    ps += __shfl_xor(ps, 4, 64);
    float a = ai_l + ps;
    a = a >= 0.f ? a : NEG_SLOPE * a;
    float ea  = __expf(a);
    float acc = ea * yself;
    float den = ea;

    int off = offs[v], dg = deg[v];
    for (int j = 0; j < dg; j += 16) {
        int idxv = 0;
        if (l < 16 && j + l < dg) idxv = elist[off + j + l];
#pragma unroll
        for (int b = 0; b < 16; ++b) {
            int s = __shfl(idxv, b, 64);
            float y = __bfloat162float(xwb[(size_t)s * 64 + l]);
            float pp = y * attj_l;
            pp += __shfl_xor(pp, 1, 64);
            pp += __shfl_xor(pp, 2, 64);
            pp += __shfl_xor(pp, 4, 64);     // aj1[s][h] on all 8 lanes of head
            float aa = ai_l + pp;
            aa = aa >= 0.f ? aa : NEG_SLOPE * aa;
            float w = (j + b < dg) ? __expf(aa) : 0.f;  // scalar condition
            acc += w * y;
            den += w;
        }
    }

    float o = acc / den + b1[l];
    o = o > 0.f ? o : expm1f(o);   // elu
    h1b[(size_t)v * 64 + l] = __float2bfloat16(o);
}

// ---------------------------------------------------------------------------
// xw2pack: packed xw2 rows [80 bf16 | 8 bf16 aj2 | pad] stride 128 u16, + ai2.
// 16 nodes/block (4 per wave), W2 staged once per block.
// ---------------------------------------------------------------------------
__global__ void __launch_bounds__(256) xw2pack_kernel(
    const __hip_bfloat16* __restrict__ h1b, const float* __restrict__ xt,
    const float* __restrict__ W2, const float* __restrict__ att2,
    __hip_bfloat16* __restrict__ xw2p, float* __restrict__ ai2, int n)
{
    __shared__ float shW2[5600];
    __shared__ float shH[4][72];
    __shared__ float shR[4][80];
    int t = threadIdx.x, wv = t >> 6, l = t & 63;
    for (int i = t; i < 5600; i += 256) shW2[i] = W2[i];
    __syncthreads();

#pragma unroll
    for (int it = 0; it < 4; ++it) {
        int v = blockIdx.x * 16 + it * 4 + wv;

        shH[wv][l] = __bfloat162float(h1b[(size_t)v * 64 + l]);
        if (l < 6) shH[wv][64 + l] = xt[(size_t)v * 6 + l];
        __builtin_amdgcn_wave_barrier();

        float a0 = 0.f, a1 = 0.f;
#pragma unroll
        for (int kk = 0; kk < 70; ++kk) {
            float f = shH[wv][kk];
            a0 += f * shW2[kk * 80 + l];
            if (l < 16) a1 += f * shW2[kk * 80 + 64 + l];
        }
        __hip_bfloat16* row = xw2p + (size_t)v * 128;
        row[l] = __float2bfloat16(a0);
        shR[wv][l] = a0;
        if (l < 16) {
            row[64 + l] = __float2bfloat16(a1);
            shR[wv][64 + l] = a1;
        }
        __builtin_amdgcn_wave_barrier();

        if (l < 16) {
            int hh = l >> 1, wj = l & 1;
            float sdot = 0.f;
#pragma unroll
            for (int cc = 0; cc < 10; ++cc)
                sdot += shR[wv][hh * 10 + cc] * att2[hh * 20 + wj * 10 + cc];
            if (wj == 0) ai2[(size_t)v * 8 + hh] = sdot;
            else         row[80 + hh] = __float2bfloat16(sdot);  // aj2 packed
        }
        __builtin_amdgcn_wave_barrier();
    }
}

// ---------------------------------------------------------------------------
// GAT layer 2 aggregation on packed rows + head-mean + b2 + log_softmax.
// One node per wave; 1 u32 gather per edge (44 lanes) + 1 shfl.
// ---------------------------------------------------------------------------
__global__ void __launch_bounds__(256) agg2_kernel(
    const unsigned* __restrict__ xw2p, const float* __restrict__ ai2,
    const float* __restrict__ b2,
    const int* __restrict__ offs, const int* __restrict__ deg,
    const int* __restrict__ elist, float* __restrict__ out, int n)
{
    __shared__ float buf[4][80];
    __shared__ float buf2[4][10];
    int t = threadIdx.x, wv = t >> 6, l = t & 63;
    int v = blockIdx.x * 4 + wv;

    bool act = l < 44;
    int hc = (l < 40) ? (l / 5) : 0;       // head of cols (2l, 2l+1)
    int ajl = 40 + (hc >> 1);              // holder lane of aj pair
    float ai_l = (l < 40) ? ai2[(size_t)v * 8 + hc] : 0.f;

    unsigned selfw = 0;
    if (act) selfw = xw2p[(size_t)v * 64 + l];
    unsigned ajw = __shfl(selfw, ajl, 64);
    float ajs = (hc & 1) ? bf_hi(ajw) : bf_lo(ajw);
    float a = ai_l + ajs;
    a = a >= 0.f ? a : NEG_SLOPE * a;
    float e0 = __expf(a);
    float acc0 = e0 * bf_lo(selfw), acc1 = e0 * bf_hi(selfw), den = e0;

    int off = offs[v], dg = deg[v];
    for (int j = 0; j < dg; j += 16) {
        int idxv = 0;
        if (l < 16 && j + l < dg) idxv = elist[off + j + l];
#pragma unroll
        for (int b = 0; b < 16; ++b) {
            int s = __shfl(idxv, b, 64);
            unsigned yw = 0;
            if (act) yw = xw2p[(size_t)s * 64 + l];
            unsigned aw = __shfl(yw, ajl, 64);
            float aj = (hc & 1) ? bf_hi(aw) : bf_lo(aw);
            float u = ai_l + aj;
            u = u >= 0.f ? u : NEG_SLOPE * u;
            float w = (j + b < dg) ? __expf(u) : 0.f;   // scalar condition
            acc0 += w * bf_lo(yw);
            acc1 += w * bf_hi(yw);
            den += w;
        }
    }

    if (l < 40) {
        float inv = 1.f / den;
        buf[wv][2 * l]     = acc0 * inv;
        buf[wv][2 * l + 1] = acc1 * inv;
    }
    __builtin_amdgcn_wave_barrier();
    if (l < 10) {
        float mval = 0.f;
#pragma unroll
        for (int hh = 0; hh < 8; ++hh) mval += buf[wv][hh * 10 + l];
        buf2[wv][l] = mval * 0.125f + b2[l];
    }
    __builtin_amdgcn_wave_barrier();
    if (l < 10) {
        float mx = -1e30f;
#pragma unroll
        for (int cc = 0; cc < 10; ++cc) mx = fmaxf(mx, buf2[wv][cc]);
        float se = 0.f;
#pragma unroll
        for (int cc = 0; cc < 10; ++cc) se += __expf(buf2[wv][cc] - mx);
        out[(size_t)v * 10 + l] = buf2[wv][l] - mx - __logf(se);
    }
}

// ---------------------------------------------------------------------------
extern "C" void kernel_launch(void* const* d_in, const int* in_sizes, int n_in,
                              void* d_out, int out_size, void* d_ws, size_t ws_size,
                              hipStream_t stream)
{
    const float* x    = (const float*)d_in[0];
    const int*   ei   = (const int*)  d_in[1];
    const float* ef   = (const float*)d_in[2];
    const float* W1   = (const float*)d_in[3];
    const float* att1 = (const float*)d_in[4];
    const float* b1   = (const float*)d_in[5];
    const float* W2   = (const float*)d_in[6];
    const float* att2 = (const float*)d_in[7];
    const float* b2   = (const float*)d_in[8];
    const float* Wq   = (const float*)d_in[9];
    const float* bq   = (const float*)d_in[10];
    const float* Wk   = (const float*)d_in[11];
    const float* bk   = (const float*)d_in[12];
    const float* Wv   = (const float*)d_in[13];
    const float* bv   = (const float*)d_in[14];
    const float* g0   = (const float*)d_in[15];
    const float* be0  = (const float*)d_in[16];
    const float* Wf1  = (const float*)d_in[17];
    const float* bf1  = (const float*)d_in[18];
    const float* Wf2  = (const float*)d_in[19];
    const float* bf2  = (const float*)d_in[20];
    const float* g1   = (const float*)d_in[21];
    const float* be1  = (const float*)d_in[22];
    const float* Wrep = (const float*)d_in[23];
    const float* brep = (const float*)d_in[24];

    const int n = in_sizes[0] / 64;   // 100000
    const int e = in_sizes[1] / 2;    // 1600000
    const int* src = ei;
    const int* dst = ei + e;

    char* ws = (char*)d_ws;
    size_t o = 0;
    auto alloc = [&](size_t bytes) -> void* {
        void* p = ws + o;
        o += (bytes + 255) & ~(size_t)255;
        return p;
    };
    __hip_bfloat16* xw1b = (__hip_bfloat16*)alloc((size_t)n * 64 * 2);
    __hip_bfloat16* h1b  = (__hip_bfloat16*)alloc((size_t)n * 64 * 2);
    __hip_bfloat16* xw2p = (__hip_bfloat16*)alloc((size_t)n * 128 * 2); // packed
    float* ai1   = (float*)alloc((size_t)n * 8 * 4);
    float* ai2   = (float*)alloc((size_t)n * 8 * 4);
    float* xt    = (float*)alloc((size_t)n * 6 * 4);
    int*   deg   = (int*)  alloc((size_t)n * 4);
    int*   offs  = (int*)  alloc((size_t)n * 4);
    int*   cur   = (int*)  alloc((size_t)n * 4);
    int*   bsum  = (int*)  alloc(256 * 4);
    int*   elist = (int*)  alloc((size_t)e * 4);
    (void)ws_size; (void)n_in; (void)out_size;

    hipMemsetAsync(deg, 0, (size_t)n * 4, stream);
    hipMemsetAsync(cur, 0, (size_t)n * 4, stream);

    const int NB = (n + 1023) / 1024;    // 98 scan blocks

    count_kernel<<<(e + 255) / 256, 256, 0, stream>>>(src, dst, deg, e);
    encoder_kernel<<<n / 8, 256, 0, stream>>>(ef, Wq, bq, Wk, bk, Wv, bv, g0, be0,
                                              Wf1, bf1, Wf2, bf2, g1, be1, Wrep, brep,
                                              xt, n);
    xw1_kernel<<<n / 16, 256, 0, stream>>>(x, W1, att1, xw1b, ai1, n);
    scan1_kernel<<<NB, 1024, 0, stream>>>(deg, bsum, n);
    scan2_kernel<<<1, 128, 0, stream>>>(bsum, NB);
    scan3_kernel<<<NB, 1024, 0, stream>>>(deg, bsum, offs, n);
    scatter_kernel<<<(e + 255) / 256, 256, 0, stream>>>(src, dst, offs, cur, elist, e);
    agg1_kernel<<<n / 4, 256, 0, stream>>>(xw1b, ai1, att1, b1,
                                           offs, deg, elist, h1b, n);
    xw2pack_kernel<<<n / 16, 256, 0, stream>>>(h1b, xt, W2, att2, xw2p, ai2, n);
    agg2_kernel<<<n / 4, 256, 0, stream>>>((const unsigned*)xw2p, ai2, b2,
                                           offs, deg, elist, (float*)d_out, n);
}